// Round 1
// baseline (433.563 us; speedup 1.0000x reference)
//
#include <hip/hip_runtime.h>
#include <hip/hip_bf16.h>

typedef __hip_bfloat16 bf16;
using bfv8 = __attribute__((ext_vector_type(8))) __bf16;
using f4_t = __attribute__((ext_vector_type(4))) float;

#define DEVI static __device__ __forceinline__

DEVI unsigned short f2bu(float f) {
    bf16 h = __float2bfloat16(f);
    return __builtin_bit_cast(unsigned short, h);
}

DEVI ushort4 f4_to_b4(float4 v) {
    ushort4 r;
    r.x = f2bu(v.x); r.y = f2bu(v.y); r.z = f2bu(v.z); r.w = f2bu(v.w);
    return r;
}

// ---------------------------------------------------------------------------
// NT GEMM: C[m][n] = sum_k A[m][k] * W[n][k]   (x @ W.T)
// tile 128x128, BK=64, 4 waves (2x2 of 64x64), 16x16x32 bf16 MFMA.
// mode 0: A fp32 (x), B = W(z) fp32, out bf16 scattered to [B,H,L,HD] (Q/K/V, z=blockIdx.z)
// mode 1: A bf16 (attn out), B = Wo fp32, out fp32 row-major [M,N] (d_out)
// ---------------------------------------------------------------------------
__global__ __launch_bounds__(256) void gemm_bt(
    const void* __restrict__ A, int a_f32,
    const float* __restrict__ B0, const float* __restrict__ B1, const float* __restrict__ B2,
    bf16* __restrict__ outb, float* __restrict__ outf, int K, int mode)
{
    constexpr int LDA = 72;  // pad 64 -> 72 elements (144B rows: 16B-aligned, banks rotate)
    __shared__ __align__(16) bf16 As[128 * LDA];
    __shared__ __align__(16) bf16 Bs[128 * LDA];

    const int tid  = threadIdx.x;
    const int lane = tid & 63, wave = tid >> 6;
    const int quad = lane >> 4, l16 = lane & 15;
    const int wr = wave >> 1, wc = wave & 1;
    const int m0 = blockIdx.y * 128, n0 = blockIdx.x * 128;
    const int z = blockIdx.z;
    const float* Bm = (z == 0) ? B0 : (z == 1) ? B1 : B2;

    f4_t zero = {0.f, 0.f, 0.f, 0.f};
    f4_t acc[4][4];
#pragma unroll
    for (int i = 0; i < 4; i++)
#pragma unroll
        for (int j = 0; j < 4; j++) acc[i][j] = zero;

    const int srow = tid >> 1, sc0 = (tid & 1) * 32;
    bf16* Asw = &As[srow * LDA + sc0];
    bf16* Bsw = &Bs[srow * LDA + sc0];
    const float* Bg  = Bm + (size_t)(n0 + srow) * K + sc0;
    const float* Agf = a_f32 ? (const float*)A + (size_t)(m0 + srow) * K + sc0 : nullptr;
    const bf16*  Agh = a_f32 ? nullptr : (const bf16*)A + (size_t)(m0 + srow) * K + sc0;

    for (int k0 = 0; k0 < K; k0 += 64) {
        if (a_f32) {
#pragma unroll
            for (int c = 0; c < 32; c += 4)
                *(ushort4*)(Asw + c) = f4_to_b4(*(const float4*)(Agf + k0 + c));
        } else {
#pragma unroll
            for (int c = 0; c < 32; c += 8)
                *(int4*)(Asw + c) = *(const int4*)(Agh + k0 + c);
        }
#pragma unroll
        for (int c = 0; c < 32; c += 4)
            *(ushort4*)(Bsw + c) = f4_to_b4(*(const float4*)(Bg + k0 + c));
        __syncthreads();

#pragma unroll
        for (int ks = 0; ks < 2; ks++) {
            bfv8 af[4], bfr[4];
#pragma unroll
            for (int mt = 0; mt < 4; mt++)
                af[mt] = *(const bfv8*)&As[(wr * 64 + mt * 16 + l16) * LDA + ks * 32 + quad * 8];
#pragma unroll
            for (int nt = 0; nt < 4; nt++)
                bfr[nt] = *(const bfv8*)&Bs[(wc * 64 + nt * 16 + l16) * LDA + ks * 32 + quad * 8];
#pragma unroll
            for (int mt = 0; mt < 4; mt++)
#pragma unroll
                for (int nt = 0; nt < 4; nt++)
                    acc[mt][nt] = __builtin_amdgcn_mfma_f32_16x16x32_bf16(af[mt], bfr[nt], acc[mt][nt], 0, 0, 0);
        }
        __syncthreads();
    }

    if (mode == 0) {
        bf16* ob = outb + (size_t)z * (4 * 16 * 1024 * 64);
#pragma unroll
        for (int mt = 0; mt < 4; mt++)
#pragma unroll
            for (int nt = 0; nt < 4; nt++)
#pragma unroll
                for (int r = 0; r < 4; r++) {
                    int m = m0 + wr * 64 + mt * 16 + quad * 4 + r;
                    int n = n0 + wc * 64 + nt * 16 + l16;
                    int b = m >> 10, l = m & 1023, h = n >> 6, hd = n & 63;
                    ob[((size_t)(b * 16 + h) * 1024 + l) * 64 + hd] = __float2bfloat16(acc[mt][nt][r]);
                }
    } else {
        const int N = gridDim.x * 128;
#pragma unroll
        for (int mt = 0; mt < 4; mt++)
#pragma unroll
            for (int nt = 0; nt < 4; nt++)
#pragma unroll
                for (int r = 0; r < 4; r++) {
                    int m = m0 + wr * 64 + mt * 16 + quad * 4 + r;
                    int n = n0 + wc * 64 + nt * 16 + l16;
                    outf[(size_t)m * N + n] = acc[mt][nt][r];
                }
    }
}

// ---------------------------------------------------------------------------
// Fused causal attention with relative position bias (keys and values).
// Grid: (16 qtiles, 64 bh). Block: 256 (4 waves, one 16-q-row strip each).
// Per 64x64 (q,k) tile:
//   S = (Q K^T + skew-gather(Q Pek^T)) / 8; online softmax;
//   O += P V + U Pev  with U[q][k-q+63] = P[q][k] (banded scatter).
// pek row for (q,k) global = (k0+kk)-(q0+qq)+1024 = ibase + (kk-qq+63), ibase=k0-q0+961.
// ---------------------------------------------------------------------------
__global__ __launch_bounds__(256) void attn_k(
    const bf16* __restrict__ Qb, const bf16* __restrict__ Kb, const bf16* __restrict__ Vb,
    const float* __restrict__ pek, const float* __restrict__ pev, bf16* __restrict__ Ob)
{
    __shared__ __align__(16) bf16 s_kv[64 * 72];    // K[kk][d] then Vt[d][kk], stride 72
    __shared__ __align__(16) bf16 s_pe[128 * 72];   // pek slice [r][d] s72, then Pvt[d][r] s136 (8704<9216)
    __shared__ __align__(16) bf16 s_tu[64 * 136];   // T[qq][c] then U[qq][r], stride 136
    __shared__ __align__(16) bf16 s_p [64 * 72];    // P[qq][kk], stride 72

    const int tid  = threadIdx.x;
    const int lane = tid & 63, wave = tid >> 6;
    const int quad = lane >> 4, l16 = lane & 15;
    const int qtile = gridDim.x - 1 - blockIdx.x;   // heaviest tiles first
    const int bh = blockIdx.y;
    const int q0 = qtile * 64;

    // Q A-fragments for this wave's 16-row strip (rows q0 + wave*16 + l16)
    bfv8 qf[2];
    {
        const bf16* qp = Qb + ((size_t)bh * 1024 + q0 + wave * 16 + l16) * 64 + quad * 8;
        qf[0] = *(const bfv8*)qp;
        qf[1] = *(const bfv8*)(qp + 32);
    }

    f4_t zero = {0.f, 0.f, 0.f, 0.f};
    f4_t o_acc[4];
    float m_i[4], l_i[4];
#pragma unroll
    for (int i = 0; i < 4; i++) { o_acc[i] = zero; m_i[i] = -1e30f; l_i[i] = 0.f; }

    for (int kt = 0; kt <= qtile; kt++) {
        const int k0 = kt * 64;
        const int ibase = k0 - q0 + 961;   // in [1, 961]; rows ibase..ibase+127 all in-table

        // ---- stage K tile and pek slice (fp32 -> bf16)
        {
            int r = tid >> 2, c0 = (tid & 3) * 16;
            const bf16* src = Kb + ((size_t)bh * 1024 + k0 + r) * 64 + c0;
            *(int4*)&s_kv[r * 72 + c0]     = *(const int4*)src;
            *(int4*)&s_kv[r * 72 + c0 + 8] = *(const int4*)(src + 8);
        }
        {
            int r = tid >> 1, c0 = (tid & 1) * 32;
            const float* src = pek + (size_t)(ibase + r) * 64 + c0;
#pragma unroll
            for (int c = 0; c < 32; c += 4)
                *(ushort4*)&s_pe[r * 72 + c0 + c] = f4_to_b4(*(const float4*)(src + c));
        }
        __syncthreads();

        // ---- S1 = Q K^T  (4 frags), T = Q Pek^T (8 frags, 64x128 across block)
        f4_t s1[4], tt[8];
#pragma unroll
        for (int i = 0; i < 4; i++) s1[i] = zero;
#pragma unroll
        for (int i = 0; i < 8; i++) tt[i] = zero;
#pragma unroll
        for (int ks = 0; ks < 2; ks++) {
#pragma unroll
            for (int nt = 0; nt < 4; nt++) {
                bfv8 kf = *(const bfv8*)&s_kv[(nt * 16 + l16) * 72 + ks * 32 + quad * 8];
                s1[nt] = __builtin_amdgcn_mfma_f32_16x16x32_bf16(qf[ks], kf, s1[nt], 0, 0, 0);
            }
#pragma unroll
            for (int nt = 0; nt < 8; nt++) {
                bfv8 pf = *(const bfv8*)&s_pe[(nt * 16 + l16) * 72 + ks * 32 + quad * 8];
                tt[nt] = __builtin_amdgcn_mfma_f32_16x16x32_bf16(qf[ks], pf, tt[nt], 0, 0, 0);
            }
        }

        // ---- write T strip (own rows only)
#pragma unroll
        for (int nt = 0; nt < 8; nt++)
#pragma unroll
            for (int r = 0; r < 4; r++)
                s_tu[(wave * 16 + quad * 4 + r) * 136 + nt * 16 + l16] = __float2bfloat16(tt[nt][r]);
        __syncthreads();

        // ---- skew gather + mask + online softmax
        float sc[4][4];
#pragma unroll
        for (int nt = 0; nt < 4; nt++)
#pragma unroll
            for (int r = 0; r < 4; r++) {
                int qq = wave * 16 + quad * 4 + r;
                int kk = nt * 16 + l16;
                float s2 = __bfloat162float(s_tu[qq * 136 + kk - qq + 63]);
                float v = (s1[nt][r] + s2) * 0.125f;
                if (kt == qtile && kk > qq) v = -1e30f;
                sc[nt][r] = v;
            }
        float alpha[4], mnew[4];
#pragma unroll
        for (int r = 0; r < 4; r++) {
            float mt = fmaxf(fmaxf(sc[0][r], sc[1][r]), fmaxf(sc[2][r], sc[3][r]));
            mt = fmaxf(mt, __shfl_xor(mt, 1));
            mt = fmaxf(mt, __shfl_xor(mt, 2));
            mt = fmaxf(mt, __shfl_xor(mt, 4));
            mt = fmaxf(mt, __shfl_xor(mt, 8));
            mnew[r] = fmaxf(m_i[r], mt);
            alpha[r] = __expf(m_i[r] - mnew[r]);
            m_i[r] = mnew[r];
        }
#pragma unroll
        for (int nt = 0; nt < 4; nt++)
#pragma unroll
            for (int r = 0; r < 4; r++)
                sc[nt][r] = __expf(sc[nt][r] - mnew[r]);
#pragma unroll
        for (int r = 0; r < 4; r++) {
            float rs = sc[0][r] + sc[1][r] + sc[2][r] + sc[3][r];
            rs += __shfl_xor(rs, 1);
            rs += __shfl_xor(rs, 2);
            rs += __shfl_xor(rs, 4);
            rs += __shfl_xor(rs, 8);
            l_i[r] = l_i[r] * alpha[r] + rs;
        }
#pragma unroll
        for (int nt = 0; nt < 4; nt++)
#pragma unroll
            for (int r = 0; r < 4; r++)
                o_acc[nt][r] *= alpha[r];

        __syncthreads();  // all waves done reading s_kv/s_pe/s_tu(T)

        // ---- restage: Vt (transposed V) and Pvt (transposed pev slice)
        {
            int r = tid >> 2, c0 = (tid & 3) * 16;
            const bf16* src = Vb + ((size_t)bh * 1024 + k0 + r) * 64 + c0;
            int4 v0 = *(const int4*)src;
            int4 v1 = *(const int4*)(src + 8);
            const bf16* e0 = (const bf16*)&v0;
            const bf16* e1 = (const bf16*)&v1;
#pragma unroll
            for (int j = 0; j < 8; j++) s_kv[(c0 + j) * 72 + r] = e0[j];
#pragma unroll
            for (int j = 0; j < 8; j++) s_kv[(c0 + 8 + j) * 72 + r] = e1[j];
        }
        {
            int r = tid >> 1, c0 = (tid & 1) * 32;
            const float* src = pev + (size_t)(ibase + r) * 64 + c0;
#pragma unroll
            for (int c = 0; c < 32; c += 4) {
                float4 v = *(const float4*)(src + c);
                s_pe[(c0 + c + 0) * 136 + r] = __float2bfloat16(v.x);
                s_pe[(c0 + c + 1) * 136 + r] = __float2bfloat16(v.y);
                s_pe[(c0 + c + 2) * 136 + r] = __float2bfloat16(v.z);
                s_pe[(c0 + c + 3) * 136 + r] = __float2bfloat16(v.w);
            }
        }
        // ---- scatter P and banded U (own strip rows). Per row qq the P band is
        // r in [63-qq, 127-qq); the (rr+64)&127 companion zero exactly covers the rest.
#pragma unroll
        for (int nt = 0; nt < 4; nt++)
#pragma unroll
            for (int r = 0; r < 4; r++) {
                int qq = wave * 16 + quad * 4 + r;
                int kk = nt * 16 + l16;
                bf16 pb = __float2bfloat16(sc[nt][r]);
                s_p[qq * 72 + kk] = pb;
                int rr = kk - qq + 63;
                s_tu[qq * 136 + rr] = pb;
                s_tu[qq * 136 + ((rr + 64) & 127)] = __float2bfloat16(0.f);
            }
        __syncthreads();

        // ---- O1 += P V ; O2 += U Pev
#pragma unroll
        for (int ks = 0; ks < 2; ks++) {
            bfv8 pa = *(const bfv8*)&s_p[(wave * 16 + l16) * 72 + ks * 32 + quad * 8];
#pragma unroll
            for (int nt = 0; nt < 4; nt++) {
                bfv8 vb = *(const bfv8*)&s_kv[(nt * 16 + l16) * 72 + ks * 32 + quad * 8];
                o_acc[nt] = __builtin_amdgcn_mfma_f32_16x16x32_bf16(pa, vb, o_acc[nt], 0, 0, 0);
            }
        }
#pragma unroll
        for (int ks = 0; ks < 4; ks++) {
            bfv8 ua = *(const bfv8*)&s_tu[(wave * 16 + l16) * 136 + ks * 32 + quad * 8];
#pragma unroll
            for (int nt = 0; nt < 4; nt++) {
                bfv8 pvb = *(const bfv8*)&s_pe[(nt * 16 + l16) * 136 + ks * 32 + quad * 8];
                o_acc[nt] = __builtin_amdgcn_mfma_f32_16x16x32_bf16(ua, pvb, o_acc[nt], 0, 0, 0);
            }
        }
        __syncthreads();  // before next iteration overwrites staging buffers
    }

    // ---- epilogue: O / l, write bf16 attn-out in [B, L, D] layout
    const int b = bh >> 4, h = bh & 15;
#pragma unroll
    for (int nt = 0; nt < 4; nt++)
#pragma unroll
        for (int r = 0; r < 4; r++) {
            int q = q0 + wave * 16 + quad * 4 + r;
            int d = nt * 16 + l16;
            float v = o_acc[nt][r] / l_i[r];
            Ob[((size_t)(b * 1024 + q)) * 1024 + h * 64 + d] = __float2bfloat16(v);
        }
}

// ---------------------------------------------------------------------------
extern "C" void kernel_launch(void* const* d_in, const int* in_sizes, int n_in,
                              void* d_out, int out_size, void* d_ws, size_t ws_size,
                              hipStream_t stream) {
    const float* x   = (const float*)d_in[0];
    const float* Wq  = (const float*)d_in[1];
    const float* Wk  = (const float*)d_in[2];
    const float* Wv  = (const float*)d_in[3];
    const float* Wo  = (const float*)d_in[4];
    const float* pek = (const float*)d_in[5];
    const float* pev = (const float*)d_in[6];

    const size_t QKV_ELEMS = (size_t)4 * 16 * 1024 * 64;  // 4 Mi elements each
    bf16* Qb = (bf16*)d_ws;           // Q,K,V contiguous (z-offset in gemm epilogue)
    bf16* Kb = Qb + QKV_ELEMS;
    bf16* Vb = Kb + QKV_ELEMS;
    bf16* Ao = Vb + QKV_ELEMS;        // attention output, [B,L,D] bf16

    // Q/K/V projections: one fused launch, z selects W and output third
    gemm_bt<<<dim3(8, 32, 3), 256, 0, stream>>>(x, 1, Wq, Wk, Wv, Qb, nullptr, 1024, 0);
    // fused causal attention + relative position bias
    attn_k<<<dim3(16, 64), 256, 0, stream>>>(Qb, Kb, Vb, pek, pev, Ao);
    // output projection -> fp32 d_out
    gemm_bt<<<dim3(8, 32, 1), 256, 0, stream>>>(Ao, 0, Wo, nullptr, nullptr, nullptr, (float*)d_out, 1024, 1);
}

// Round 2
// 363.980 us; speedup vs baseline: 1.1912x; 1.1912x over previous
//
#include <hip/hip_runtime.h>
#include <hip/hip_bf16.h>

typedef __hip_bfloat16 bf16;
using bfv8 = __attribute__((ext_vector_type(8))) __bf16;
using f4_t = __attribute__((ext_vector_type(4))) float;

#define DEVI static __device__ __forceinline__

DEVI unsigned short f2bu(float f) {
    bf16 h = __float2bfloat16(f);
    return __builtin_bit_cast(unsigned short, h);
}
DEVI ushort4 f4_to_b4(float4 v) {
    ushort4 r;
    r.x = f2bu(v.x); r.y = f2bu(v.y); r.z = f2bu(v.z); r.w = f2bu(v.w);
    return r;
}
DEVI void gl2lds16(const void* g, void* l) {
    __builtin_amdgcn_global_load_lds((const __attribute__((address_space(1))) void*)g,
                                     (__attribute__((address_space(3))) void*)l, 16, 0, 0);
}

// ---------------------------------------------------------------------------
// prep_cast: fp32 -> bf16 for x (4M elems) and Wq/Wk/Wv/Wo (1M each).
// One float4 per thread; 8192 blocks x 256.
// ---------------------------------------------------------------------------
__global__ __launch_bounds__(256) void prep_cast(
    const float* __restrict__ x, const float* __restrict__ wq, const float* __restrict__ wk,
    const float* __restrict__ wv, const float* __restrict__ wo,
    bf16* __restrict__ xb, bf16* __restrict__ wqb, bf16* __restrict__ wkb,
    bf16* __restrict__ wvb, bf16* __restrict__ wob)
{
    size_t i = (size_t)blockIdx.x * 256 + threadIdx.x;   // float4 index
    const size_t X4 = 1u << 20, W4 = 1u << 18;
    const float* src; bf16* dst; size_t off;
    if (i < X4)              { src = x;  dst = xb;  off = i; }
    else if (i < X4 + W4)    { src = wq; dst = wqb; off = i - X4; }
    else if (i < X4 + 2*W4)  { src = wk; dst = wkb; off = i - X4 - W4; }
    else if (i < X4 + 3*W4)  { src = wv; dst = wvb; off = i - X4 - 2*W4; }
    else                     { src = wo; dst = wob; off = i - X4 - 3*W4; }
    float4 v = ((const float4*)src)[off];
    ((ushort4*)dst)[off] = f4_to_b4(v);
}

// ---------------------------------------------------------------------------
// prep_tables: pekb[j][d] = bf16(pek[j][d]) (j<2049, row-major, 128B rows);
// pevTs[d][j] = bf16(pev[j+1][d]) (transposed, column shift -1 so that the
// always-odd jbase becomes an even, 16B-aligned stored column).
// ---------------------------------------------------------------------------
__global__ void prep_tables(const float* __restrict__ pek, const float* __restrict__ pev,
                            bf16* __restrict__ pekb, bf16* __restrict__ pevTs)
{
    int j = blockIdx.x, d = threadIdx.x;   // grid 2049 x 64
    pekb[j * 64 + d] = __float2bfloat16(pek[j * 64 + d]);
    if (j >= 1) pevTs[(size_t)d * 2048 + (j - 1)] = __float2bfloat16(pev[j * 64 + d]);
}

// ---------------------------------------------------------------------------
// transpose_v: Vb [bh][l][d] -> Vtb [bh][d][l], 64x64 LDS tiles.
// ---------------------------------------------------------------------------
__global__ __launch_bounds__(256) void transpose_v(const bf16* __restrict__ Vb, bf16* __restrict__ Vtb)
{
    __shared__ __align__(16) bf16 t[64][72];
    const int bh = blockIdx.y, l0 = blockIdx.x * 64;
    const int r = threadIdx.x >> 2, c0 = (threadIdx.x & 3) * 16;
    const bf16* src = Vb + ((size_t)(bh << 10) + l0 + r) * 64 + c0;
    *(int4*)&t[r][c0]     = *(const int4*)src;
    *(int4*)&t[r][c0 + 8] = *(const int4*)(src + 8);
    __syncthreads();
    int4 o[2]; bf16* ob = (bf16*)o;
#pragma unroll
    for (int j = 0; j < 16; j++) ob[j] = t[c0 + j][r];
    bf16* dst = Vtb + ((size_t)(bh << 6) + r) * 1024 + l0 + c0;
    *(int4*)dst = o[0]; *(int4*)(dst + 8) = o[1];
}

// ---------------------------------------------------------------------------
// NT GEMM (m97 structure): C[m][n] = sum_k A[m][k]*B[n][k], A/B bf16.
// 128x128 tile, BK=64, 4 waves 2x2, unpadded LDS, global_load_lds width=16.
// mode 0: out bf16 scattered to [B,H,L,HD] (Q/K/V; z selects W and out third)
// mode 1: out fp32 row-major [M,1024] (final projection)
// ---------------------------------------------------------------------------
__global__ __launch_bounds__(256) void gemm_bt2(
    const bf16* __restrict__ A,
    const bf16* __restrict__ B0, const bf16* __restrict__ B1, const bf16* __restrict__ B2,
    bf16* __restrict__ outb, float* __restrict__ outf, int K, int mode)
{
    __shared__ __align__(16) bf16 As[128 * 64];
    __shared__ __align__(16) bf16 Bs[128 * 64];

    const int tid  = threadIdx.x;
    const int lane = tid & 63, wave = tid >> 6;
    const int quad = lane >> 4, l16 = lane & 15;
    const int wr = wave >> 1, wc = wave & 1;
    const int m0 = blockIdx.y * 128, n0 = blockIdx.x * 128;
    const int z = blockIdx.z;
    const bf16* Bm = (z == 0) ? B0 : (z == 1) ? B1 : B2;

    f4_t zero = {0.f, 0.f, 0.f, 0.f};
    f4_t acc[4][4];
#pragma unroll
    for (int i = 0; i < 4; i++)
#pragma unroll
        for (int j = 0; j < 4; j++) acc[i][j] = zero;

    // staging: wave w covers rows [32w,32w+32); instr i covers 8 rows; lane j ->
    // row +j/8, col (j&7)*8 elems  (LDS dest = uniform base + lane*16B, contiguous)
    const int srow = 32 * wave + (lane >> 3);
    const int scol = (lane & 7) * 8;
    const bf16* Ag = A  + (size_t)(m0 + srow) * K + scol;
    const bf16* Bg = Bm + (size_t)(n0 + srow) * K + scol;

    for (int k0 = 0; k0 < K; k0 += 64) {
#pragma unroll
        for (int i = 0; i < 4; i++) {
            gl2lds16(Ag + (size_t)(8 * i) * K + k0, &As[(32 * wave + 8 * i) * 64]);
            gl2lds16(Bg + (size_t)(8 * i) * K + k0, &Bs[(32 * wave + 8 * i) * 64]);
        }
        __syncthreads();
#pragma unroll
        for (int ks = 0; ks < 2; ks++) {
            bfv8 af[4], bfr[4];
#pragma unroll
            for (int mt = 0; mt < 4; mt++)
                af[mt] = *(const bfv8*)&As[(wr * 64 + mt * 16 + l16) * 64 + ks * 32 + quad * 8];
#pragma unroll
            for (int nt = 0; nt < 4; nt++)
                bfr[nt] = *(const bfv8*)&Bs[(wc * 64 + nt * 16 + l16) * 64 + ks * 32 + quad * 8];
#pragma unroll
            for (int mt = 0; mt < 4; mt++)
#pragma unroll
                for (int nt = 0; nt < 4; nt++)
                    acc[mt][nt] = __builtin_amdgcn_mfma_f32_16x16x32_bf16(af[mt], bfr[nt], acc[mt][nt], 0, 0, 0);
        }
        __syncthreads();
    }

    if (mode == 0) {
        bf16* ob = outb + (size_t)z * (4 * 16 * 1024 * 64);
#pragma unroll
        for (int mt = 0; mt < 4; mt++)
#pragma unroll
            for (int nt = 0; nt < 4; nt++)
#pragma unroll
                for (int r = 0; r < 4; r++) {
                    int m = m0 + wr * 64 + mt * 16 + quad * 4 + r;
                    int n = n0 + wc * 64 + nt * 16 + l16;
                    int b = m >> 10, l = m & 1023, h = n >> 6, hd = n & 63;
                    ob[((size_t)(b * 16 + h) * 1024 + l) * 64 + hd] = __float2bfloat16(acc[mt][nt][r]);
                }
    } else {
#pragma unroll
        for (int mt = 0; mt < 4; mt++)
#pragma unroll
            for (int nt = 0; nt < 4; nt++)
#pragma unroll
                for (int r = 0; r < 4; r++) {
                    int m = m0 + wr * 64 + mt * 16 + quad * 4 + r;
                    int n = n0 + wc * 64 + nt * 16 + l16;
                    outf[(size_t)m * 1024 + n] = acc[mt][nt][r];
                }
    }
}

// ---------------------------------------------------------------------------
// attn_k v2: one wave per block, one 16-q-row strip per wave, 64-wide k tiles.
// Zero barriers: all LDS (skew T/U, P) is private to the wave.
// B-fragments (K, pekb, Vt, pevTs) load directly from global (L2-hot).
// Per tile: S = scaled(Q K^T) + skew-gather(scaled(Q) Pek^T); online softmax;
//           O += P V + U Pev  with U[qq][kk-qq+15] = P[qq][kk], K-dim padded to 96.
// pek row for (q,k) = (k-q)+1024 = jbase + (kk-qq+15), jbase = 64kt - 16s + 1009 (odd).
// ---------------------------------------------------------------------------
__global__ __launch_bounds__(64) void attn_k(
    const bf16* __restrict__ Qb, const bf16* __restrict__ Kb, const bf16* __restrict__ Vtb,
    const bf16* __restrict__ pekb, const bf16* __restrict__ pevTs, bf16* __restrict__ Ob)
{
    constexpr int ST = 104;                       // sT stride (208B rows: 16B-aligned, 2-way banks)
    __shared__ __align__(16) bf16 sT[16 * ST];    // T (16x80) then U (16x96)
    __shared__ __align__(16) bf16 sP[16 * 72];    // P (16x64)

    const int lane = threadIdx.x;
    const int quad = lane >> 4, l16 = lane & 15;
    const int s  = 63 - ((blockIdx.x + blockIdx.y) & 63);   // strip swizzle, heavy-first
    const int bh = blockIdx.y;
    const int nkt = (s >> 2) + 1;

    // Q A-fragments, pre-scaled by 1/8 (exact power of 2)
    bfv8 qf[2];
    {
        const bf16* qp = Qb + ((size_t)bh * 1024 + 16 * s + l16) * 64 + quad * 8;
        qf[0] = *(const bfv8*)qp;
        qf[1] = *(const bfv8*)(qp + 32);
#pragma unroll
        for (int j = 0; j < 8; j++) {
            qf[0][j] = (__bf16)((float)qf[0][j] * 0.125f);
            qf[1][j] = (__bf16)((float)qf[1][j] * 0.125f);
        }
    }

    f4_t zero = {0.f, 0.f, 0.f, 0.f};
    f4_t o_acc[4];
    float m_i[4], l_i[4];
#pragma unroll
    for (int i = 0; i < 4; i++) { o_acc[i] = zero; m_i[i] = -1e30f; l_i[i] = 0.f; }

    const bf16* Kbh = Kb  + (size_t)bh * 1024 * 64;
    const bf16* Vbh = Vtb + (size_t)bh * 64 * 1024;

    for (int kt = 0; kt < nkt; kt++) {
        const int k0 = kt << 6;
        const int jbase = k0 - 16 * s + 1009;     // odd, in [1, 1009]

        // ---- S1 = Qs K^T (4 frags), T = Qs Pek^T (5 frags, width 80)
        f4_t s1[4], tt[5];
#pragma unroll
        for (int i = 0; i < 4; i++) s1[i] = zero;
#pragma unroll
        for (int i = 0; i < 5; i++) tt[i] = zero;
#pragma unroll
        for (int ks = 0; ks < 2; ks++) {
#pragma unroll
            for (int nt = 0; nt < 4; nt++) {
                bfv8 kf = *(const bfv8*)&Kbh[(size_t)(k0 + nt * 16 + l16) * 64 + ks * 32 + quad * 8];
                s1[nt] = __builtin_amdgcn_mfma_f32_16x16x32_bf16(qf[ks], kf, s1[nt], 0, 0, 0);
            }
#pragma unroll
            for (int nt = 0; nt < 5; nt++) {
                bfv8 pf = *(const bfv8*)&pekb[(size_t)(jbase + nt * 16 + l16) * 64 + ks * 32 + quad * 8];
                tt[nt] = __builtin_amdgcn_mfma_f32_16x16x32_bf16(qf[ks], pf, tt[nt], 0, 0, 0);
            }
        }

        // ---- write T (own rows; intra-wave lgkmcnt ordering, no barrier)
#pragma unroll
        for (int nt = 0; nt < 5; nt++)
#pragma unroll
            for (int r = 0; r < 4; r++)
                sT[(quad * 4 + r) * ST + nt * 16 + l16] = __float2bfloat16(tt[nt][r]);

        // ---- skew gather + causal mask (already scaled)
        float sc[4][4];
#pragma unroll
        for (int nt = 0; nt < 4; nt++)
#pragma unroll
            for (int r = 0; r < 4; r++) {
                int qq = quad * 4 + r;
                int kk = nt * 16 + l16;
                float s2 = __bfloat162float(sT[qq * ST + kk - qq + 15]);
                float v = s1[nt][r] + s2;
                if (k0 + kk > 16 * s + qq) v = -1e30f;
                sc[nt][r] = v;
            }

        // ---- online softmax (row = fixed quad; reduce over l16 via xor<16)
        float alpha[4];
#pragma unroll
        for (int r = 0; r < 4; r++) {
            float mt = fmaxf(fmaxf(sc[0][r], sc[1][r]), fmaxf(sc[2][r], sc[3][r]));
            mt = fmaxf(mt, __shfl_xor(mt, 1));
            mt = fmaxf(mt, __shfl_xor(mt, 2));
            mt = fmaxf(mt, __shfl_xor(mt, 4));
            mt = fmaxf(mt, __shfl_xor(mt, 8));
            float mnew = fmaxf(m_i[r], mt);
            alpha[r] = __expf(m_i[r] - mnew);
            m_i[r] = mnew;
        }
#pragma unroll
        for (int nt = 0; nt < 4; nt++)
#pragma unroll
            for (int r = 0; r < 4; r++)
                sc[nt][r] = __expf(sc[nt][r] - m_i[r]);
#pragma unroll
        for (int r = 0; r < 4; r++) {
            float rs = sc[0][r] + sc[1][r] + sc[2][r] + sc[3][r];
            rs += __shfl_xor(rs, 1);
            rs += __shfl_xor(rs, 2);
            rs += __shfl_xor(rs, 4);
            rs += __shfl_xor(rs, 8);
            l_i[r] = l_i[r] * alpha[r] + rs;
#pragma unroll
            for (int nt = 0; nt < 4; nt++) o_acc[nt][r] *= alpha[r];
        }

        // ---- zero U region (16 x 96), after the gather reads (in-order DS pipe)
        {
            int zr = lane >> 2, zc = (lane & 3) * 24;
            int4 zi = {0, 0, 0, 0};
#pragma unroll
            for (int j = 0; j < 3; j++)
                *(int4*)&sT[zr * ST + zc + j * 8] = zi;
        }
        // ---- scatter P and banded U
#pragma unroll
        for (int nt = 0; nt < 4; nt++)
#pragma unroll
            for (int r = 0; r < 4; r++) {
                int qq = quad * 4 + r;
                int kk = nt * 16 + l16;
                bf16 pb = __float2bfloat16(sc[nt][r]);
                sP[qq * 72 + kk] = pb;
                sT[qq * ST + kk - qq + 15] = pb;
            }

        // ---- O += P V  (K=64) ; O += U Pev (K=96, cols 80..95 zero)
#pragma unroll
        for (int ks = 0; ks < 2; ks++) {
            bfv8 pa = *(const bfv8*)&sP[l16 * 72 + ks * 32 + quad * 8];
#pragma unroll
            for (int nt = 0; nt < 4; nt++) {
                bfv8 vf = *(const bfv8*)&Vbh[(size_t)(nt * 16 + l16) * 1024 + k0 + ks * 32 + quad * 8];
                o_acc[nt] = __builtin_amdgcn_mfma_f32_16x16x32_bf16(pa, vf, o_acc[nt], 0, 0, 0);
            }
        }
#pragma unroll
        for (int ks = 0; ks < 3; ks++) {
            bfv8 ua = *(const bfv8*)&sT[l16 * ST + ks * 32 + quad * 8];
#pragma unroll
            for (int nt = 0; nt < 4; nt++) {
                bfv8 pvf = *(const bfv8*)&pevTs[(size_t)(nt * 16 + l16) * 2048 + (jbase - 1) + ks * 32 + quad * 8];
                o_acc[nt] = __builtin_amdgcn_mfma_f32_16x16x32_bf16(ua, pvf, o_acc[nt], 0, 0, 0);
            }
        }
    }

    // ---- epilogue: O / l, write bf16 attn-out in [B, L, D] layout
    const int b = bh >> 4, h = bh & 15;
#pragma unroll
    for (int nt = 0; nt < 4; nt++)
#pragma unroll
        for (int r = 0; r < 4; r++) {
            int q = 16 * s + quad * 4 + r;
            int d = nt * 16 + l16;
            Ob[((size_t)(b * 1024 + q)) * 1024 + h * 64 + d] = __float2bfloat16(o_acc[nt][r] / l_i[r]);
        }
}

// ---------------------------------------------------------------------------
extern "C" void kernel_launch(void* const* d_in, const int* in_sizes, int n_in,
                              void* d_out, int out_size, void* d_ws, size_t ws_size,
                              hipStream_t stream) {
    const float* x   = (const float*)d_in[0];
    const float* Wq  = (const float*)d_in[1];
    const float* Wk  = (const float*)d_in[2];
    const float* Wv  = (const float*)d_in[3];
    const float* Wo  = (const float*)d_in[4];
    const float* pek = (const float*)d_in[5];
    const float* pev = (const float*)d_in[6];

    const size_t MB = 1u << 20;
    char* ws = (char*)d_ws;
    bf16* xb    = (bf16*)(ws + 0);          // 8 MB; dead after QKV gemm -> reused as Ao
    bf16* Wqb   = (bf16*)(ws + 8  * MB);    // 2 MB each
    bf16* Wkb   = (bf16*)(ws + 10 * MB);
    bf16* Wvb   = (bf16*)(ws + 12 * MB);
    bf16* Wob   = (bf16*)(ws + 14 * MB);
    bf16* Qb    = (bf16*)(ws + 16 * MB);    // Q,K,V contiguous (z-offset in gemm epilogue)
    bf16* Kb    = (bf16*)(ws + 24 * MB);
    bf16* Vb    = (bf16*)(ws + 32 * MB);
    bf16* Vtb   = (bf16*)(ws + 40 * MB);
    bf16* pekb  = (bf16*)(ws + 48 * MB);            // 2049*64*2 B
    bf16* pevTs = (bf16*)(ws + 48 * MB + 512*1024); // 64*2048*2 B
    bf16* Ao    = xb;                               // aliased: x dead by then

    prep_cast<<<dim3(8192), 256, 0, stream>>>(x, Wq, Wk, Wv, Wo, xb, Wqb, Wkb, Wvb, Wob);
    prep_tables<<<dim3(2049), 64, 0, stream>>>(pek, pev, pekb, pevTs);
    gemm_bt2<<<dim3(8, 32, 3), 256, 0, stream>>>(xb, Wqb, Wkb, Wvb, Qb, nullptr, 1024, 0);
    transpose_v<<<dim3(16, 64), 256, 0, stream>>>(Vb, Vtb);
    attn_k<<<dim3(64, 64), 64, 0, stream>>>(Qb, Kb, Vtb, pekb, pevTs, Ao);
    gemm_bt2<<<dim3(8, 32, 1), 256, 0, stream>>>(Ao, Wob, nullptr, nullptr, nullptr, (float*)d_out, 1024, 1);
}

// Round 3
// 325.061 us; speedup vs baseline: 1.3338x; 1.1197x over previous
//
#include <hip/hip_runtime.h>
#include <hip/hip_bf16.h>

typedef __hip_bfloat16 bf16;
using bfv8 = __attribute__((ext_vector_type(8))) __bf16;
using f4_t = __attribute__((ext_vector_type(4))) float;

#define DEVI static __device__ __forceinline__

DEVI unsigned short f2bu(float f) {
    bf16 h = __float2bfloat16(f);
    return __builtin_bit_cast(unsigned short, h);
}
DEVI ushort4 f4_to_b4(float4 v) {
    ushort4 r;
    r.x = f2bu(v.x); r.y = f2bu(v.y); r.z = f2bu(v.z); r.w = f2bu(v.w);
    return r;
}
DEVI void gl2lds16(const void* g, void* l) {
    __builtin_amdgcn_global_load_lds((const __attribute__((address_space(1))) void*)g,
                                     (__attribute__((address_space(3))) void*)l, 16, 0, 0);
}

// ---------------------------------------------------------------------------
// prep_cast: fp32 -> bf16 for x (4M elems) and Wq/Wk/Wv/Wo (1M each).
// ---------------------------------------------------------------------------
__global__ __launch_bounds__(256) void prep_cast(
    const float* __restrict__ x, const float* __restrict__ wq, const float* __restrict__ wk,
    const float* __restrict__ wv, const float* __restrict__ wo,
    bf16* __restrict__ xb, bf16* __restrict__ wqb, bf16* __restrict__ wkb,
    bf16* __restrict__ wvb, bf16* __restrict__ wob)
{
    size_t i = (size_t)blockIdx.x * 256 + threadIdx.x;   // float4 index
    const size_t X4 = 1u << 20, W4 = 1u << 18;
    const float* src; bf16* dst; size_t off;
    if (i < X4)              { src = x;  dst = xb;  off = i; }
    else if (i < X4 + W4)    { src = wq; dst = wqb; off = i - X4; }
    else if (i < X4 + 2*W4)  { src = wk; dst = wkb; off = i - X4 - W4; }
    else if (i < X4 + 3*W4)  { src = wv; dst = wvb; off = i - X4 - 2*W4; }
    else                     { src = wo; dst = wob; off = i - X4 - 3*W4; }
    float4 v = ((const float4*)src)[off];
    ((ushort4*)dst)[off] = f4_to_b4(v);
}

// ---------------------------------------------------------------------------
// prep_tables: pekb[j][d] = bf16(pek[j][d]); pevTs[d][j] = bf16(pev[j+1][d])
// (transposed, -1 column shift so even jbase-1 gives 16B-aligned loads).
// ---------------------------------------------------------------------------
__global__ void prep_tables(const float* __restrict__ pek, const float* __restrict__ pev,
                            bf16* __restrict__ pekb, bf16* __restrict__ pevTs)
{
    int j = blockIdx.x, d = threadIdx.x;   // grid 2049 x 64
    pekb[j * 64 + d] = __float2bfloat16(pek[j * 64 + d]);
    if (j >= 1) pevTs[(size_t)d * 2048 + (j - 1)] = __float2bfloat16(pev[j * 64 + d]);
}

// ---------------------------------------------------------------------------
// transpose_v: Vb [bh][l][d] -> Vtb [bh][d][l], 64x64 LDS tiles.
// ---------------------------------------------------------------------------
__global__ __launch_bounds__(256) void transpose_v(const bf16* __restrict__ Vb, bf16* __restrict__ Vtb)
{
    __shared__ __align__(16) bf16 t[64][72];
    const int bh = blockIdx.y, l0 = blockIdx.x * 64;
    const int r = threadIdx.x >> 2, c0 = (threadIdx.x & 3) * 16;
    const bf16* src = Vb + ((size_t)(bh << 10) + l0 + r) * 64 + c0;
    *(int4*)&t[r][c0]     = *(const int4*)src;
    *(int4*)&t[r][c0 + 8] = *(const int4*)(src + 8);
    __syncthreads();
    int4 o[2]; bf16* ob = (bf16*)o;
#pragma unroll
    for (int j = 0; j < 16; j++) ob[j] = t[c0 + j][r];
    bf16* dst = Vtb + ((size_t)(bh << 6) + r) * 1024 + l0 + c0;
    *(int4*)dst = o[0]; *(int4*)(dst + 8) = o[1];
}

// ---------------------------------------------------------------------------
// NT GEMM (m97 structure): C[m][n] = sum_k A[m][k]*B[n][k], A/B bf16.
// 128x128 tile, BK=64, 4 waves 2x2, global_load_lds width=16.
// ---------------------------------------------------------------------------
__global__ __launch_bounds__(256) void gemm_bt2(
    const bf16* __restrict__ A,
    const bf16* __restrict__ B0, const bf16* __restrict__ B1, const bf16* __restrict__ B2,
    bf16* __restrict__ outb, float* __restrict__ outf, int K, int mode)
{
    __shared__ __align__(16) bf16 As[128 * 64];
    __shared__ __align__(16) bf16 Bs[128 * 64];

    const int tid  = threadIdx.x;
    const int lane = tid & 63, wave = tid >> 6;
    const int quad = lane >> 4, l16 = lane & 15;
    const int wr = wave >> 1, wc = wave & 1;
    const int m0 = blockIdx.y * 128, n0 = blockIdx.x * 128;
    const int z = blockIdx.z;
    const bf16* Bm = (z == 0) ? B0 : (z == 1) ? B1 : B2;

    f4_t zero = {0.f, 0.f, 0.f, 0.f};
    f4_t acc[4][4];
#pragma unroll
    for (int i = 0; i < 4; i++)
#pragma unroll
        for (int j = 0; j < 4; j++) acc[i][j] = zero;

    const int srow = 32 * wave + (lane >> 3);
    const int scol = (lane & 7) * 8;
    const bf16* Ag = A  + (size_t)(m0 + srow) * K + scol;
    const bf16* Bg = Bm + (size_t)(n0 + srow) * K + scol;

    for (int k0 = 0; k0 < K; k0 += 64) {
#pragma unroll
        for (int i = 0; i < 4; i++) {
            gl2lds16(Ag + (size_t)(8 * i) * K + k0, &As[(32 * wave + 8 * i) * 64]);
            gl2lds16(Bg + (size_t)(8 * i) * K + k0, &Bs[(32 * wave + 8 * i) * 64]);
        }
        __syncthreads();
#pragma unroll
        for (int ks = 0; ks < 2; ks++) {
            bfv8 af[4], bfr[4];
#pragma unroll
            for (int mt = 0; mt < 4; mt++)
                af[mt] = *(const bfv8*)&As[(wr * 64 + mt * 16 + l16) * 64 + ks * 32 + quad * 8];
#pragma unroll
            for (int nt = 0; nt < 4; nt++)
                bfr[nt] = *(const bfv8*)&Bs[(wc * 64 + nt * 16 + l16) * 64 + ks * 32 + quad * 8];
#pragma unroll
            for (int mt = 0; mt < 4; mt++)
#pragma unroll
                for (int nt = 0; nt < 4; nt++)
                    acc[mt][nt] = __builtin_amdgcn_mfma_f32_16x16x32_bf16(af[mt], bfr[nt], acc[mt][nt], 0, 0, 0);
        }
        __syncthreads();
    }

    if (mode == 0) {
        bf16* ob = outb + (size_t)z * (4 * 16 * 1024 * 64);
#pragma unroll
        for (int mt = 0; mt < 4; mt++)
#pragma unroll
            for (int nt = 0; nt < 4; nt++)
#pragma unroll
                for (int r = 0; r < 4; r++) {
                    int m = m0 + wr * 64 + mt * 16 + quad * 4 + r;
                    int n = n0 + wc * 64 + nt * 16 + l16;
                    int b = m >> 10, l = m & 1023, h = n >> 6, hd = n & 63;
                    ob[((size_t)(b * 16 + h) * 1024 + l) * 64 + hd] = __float2bfloat16(acc[mt][nt][r]);
                }
    } else {
#pragma unroll
        for (int mt = 0; mt < 4; mt++)
#pragma unroll
            for (int nt = 0; nt < 4; nt++)
#pragma unroll
                for (int r = 0; r < 4; r++) {
                    int m = m0 + wr * 64 + mt * 16 + quad * 4 + r;
                    int n = n0 + wc * 64 + nt * 16 + l16;
                    outf[(size_t)m * 1024 + n] = acc[mt][nt][r];
                }
    }
}

// ---------------------------------------------------------------------------
// attn_k v3: 4 independent waves per 256-thread block (no barriers at all).
// Wave w handles strip s = 63-blockIdx.y of bh = blockIdx.x*4+w: all waves in
// a block have identical tile counts (perfect balance) and share pek/pev L2.
// Skew gather is done with ds_bpermute shuffles (T never touches LDS):
//   S2[qq][kk] = T[qq][kk-qq+15]; row qq lives in quad qq>>2, reg r=qq&3, so
//   the gather is an intra-quad 16-lane rotation by 15-qq + 2-frag select.
// U's zero complement is tile-invariant -> zeroed ONCE before the k-loop.
// ---------------------------------------------------------------------------
__global__ __launch_bounds__(256) void attn_k(
    const bf16* __restrict__ Qb, const bf16* __restrict__ Kb, const bf16* __restrict__ Vtb,
    const bf16* __restrict__ pekb, const bf16* __restrict__ pevTs, bf16* __restrict__ Ob)
{
    constexpr int ST = 104;                       // U stride (208B rows, 16B-aligned)
    __shared__ __align__(16) bf16 sU[4][16 * ST]; // banded U (16x96 used)
    __shared__ __align__(16) bf16 sP[4][16 * 72]; // P (16x64)

    const int tid  = threadIdx.x;
    const int lane = tid & 63, wave = tid >> 6;
    const int quad = lane >> 4, l16 = lane & 15;
    const int s  = 63 - blockIdx.y;               // heavy strips dispatched first
    const int bh = blockIdx.x * 4 + wave;
    const int nkt = (s >> 2) + 1;

    bf16* myU = sU[wave];
    bf16* myP = sP[wave];

    // ---- zero U once (the band positions are tile-invariant; complement stays 0)
    {
        int* p = (int*)myU;
#pragma unroll
        for (int i = 0; i < 13; i++) p[lane + 64 * i] = 0;
    }

    // ---- Q A-fragments, pre-scaled by 1/8
    bfv8 qf[2];
    {
        const bf16* qp = Qb + ((size_t)bh * 1024 + 16 * s + l16) * 64 + quad * 8;
        qf[0] = *(const bfv8*)qp;
        qf[1] = *(const bfv8*)(qp + 32);
#pragma unroll
        for (int j = 0; j < 8; j++) {
            qf[0][j] = (__bf16)((float)qf[0][j] * 0.125f);
            qf[1][j] = (__bf16)((float)qf[1][j] * 0.125f);
        }
    }

    f4_t zero = {0.f, 0.f, 0.f, 0.f};
    f4_t o_acc[4];
    float m_i[4], l_i[4];
#pragma unroll
    for (int i = 0; i < 4; i++) { o_acc[i] = zero; m_i[i] = -1e30f; l_i[i] = 0.f; }

    const bf16* Kbh = Kb  + (size_t)bh * 1024 * 64;
    const bf16* Vbh = Vtb + (size_t)bh * 64 * 1024;

    for (int kt = 0; kt < nkt; kt++) {
        const int k0 = kt << 6;
        const int jbase = k0 - 16 * s + 1009;     // odd, in [1, 1009]

        // ---- S1 = Qs K^T (4 frags), T = Qs Pek^T (5 frags, width 80)
        f4_t s1[4], tt[5];
#pragma unroll
        for (int i = 0; i < 4; i++) s1[i] = zero;
#pragma unroll
        for (int i = 0; i < 5; i++) tt[i] = zero;
#pragma unroll
        for (int ks = 0; ks < 2; ks++) {
#pragma unroll
            for (int nt = 0; nt < 4; nt++) {
                bfv8 kf = *(const bfv8*)&Kbh[(size_t)(k0 + nt * 16 + l16) * 64 + ks * 32 + quad * 8];
                s1[nt] = __builtin_amdgcn_mfma_f32_16x16x32_bf16(qf[ks], kf, s1[nt], 0, 0, 0);
            }
#pragma unroll
            for (int nt = 0; nt < 5; nt++) {
                bfv8 pf = *(const bfv8*)&pekb[(size_t)(jbase + nt * 16 + l16) * 64 + ks * 32 + quad * 8];
                tt[nt] = __builtin_amdgcn_mfma_f32_16x16x32_bf16(qf[ks], pf, tt[nt], 0, 0, 0);
            }
        }

        // ---- skew gather via shuffles + causal mask (all pre-scaled)
        float sc[4][4];
#pragma unroll
        for (int r = 0; r < 4; r++) {
            int qq = quad * 4 + r;
            int t  = l16 + 15 - qq;                    // in [0,30]
            int srcl = quad * 16 + (t & 15);
            bool lo = (t < 16);
#pragma unroll
            for (int nt = 0; nt < 4; nt++) {
                float a = __shfl(tt[nt][r], srcl, 64);
                float b = __shfl(tt[nt + 1][r], srcl, 64);
                float s2 = lo ? a : b;
                float v = s1[nt][r] + s2;
                int kk = nt * 16 + l16;
                if (k0 + kk > 16 * s + qq) v = -1e30f;
                sc[nt][r] = v;
            }
        }

        // ---- online softmax (row = quad*4+r; reduce over l16 via xor<16)
        float alpha[4];
#pragma unroll
        for (int r = 0; r < 4; r++) {
            float mt = fmaxf(fmaxf(sc[0][r], sc[1][r]), fmaxf(sc[2][r], sc[3][r]));
            mt = fmaxf(mt, __shfl_xor(mt, 1));
            mt = fmaxf(mt, __shfl_xor(mt, 2));
            mt = fmaxf(mt, __shfl_xor(mt, 4));
            mt = fmaxf(mt, __shfl_xor(mt, 8));
            float mnew = fmaxf(m_i[r], mt);
            alpha[r] = __expf(m_i[r] - mnew);
            m_i[r] = mnew;
        }
#pragma unroll
        for (int nt = 0; nt < 4; nt++)
#pragma unroll
            for (int r = 0; r < 4; r++)
                sc[nt][r] = __expf(sc[nt][r] - m_i[r]);
#pragma unroll
        for (int r = 0; r < 4; r++) {
            float rs = sc[0][r] + sc[1][r] + sc[2][r] + sc[3][r];
            rs += __shfl_xor(rs, 1);
            rs += __shfl_xor(rs, 2);
            rs += __shfl_xor(rs, 4);
            rs += __shfl_xor(rs, 8);
            l_i[r] = l_i[r] * alpha[r] + rs;
#pragma unroll
            for (int nt = 0; nt < 4; nt++) o_acc[nt][r] *= alpha[r];
        }

        // ---- scatter P (row-major) and banded U (band cols are tile-invariant)
#pragma unroll
        for (int nt = 0; nt < 4; nt++)
#pragma unroll
            for (int r = 0; r < 4; r++) {
                int qq = quad * 4 + r;
                int kk = nt * 16 + l16;
                bf16 pb = __float2bfloat16(sc[nt][r]);
                myP[qq * 72 + kk] = pb;
                myU[qq * ST + kk - qq + 15] = pb;
            }

        // ---- O += P V (K=64) ; O += U Pev (K=96, zeros outside band)
#pragma unroll
        for (int ks = 0; ks < 2; ks++) {
            bfv8 pa = *(const bfv8*)&myP[l16 * 72 + ks * 32 + quad * 8];
#pragma unroll
            for (int nt = 0; nt < 4; nt++) {
                bfv8 vf = *(const bfv8*)&Vbh[(size_t)(nt * 16 + l16) * 1024 + k0 + ks * 32 + quad * 8];
                o_acc[nt] = __builtin_amdgcn_mfma_f32_16x16x32_bf16(pa, vf, o_acc[nt], 0, 0, 0);
            }
        }
#pragma unroll
        for (int ks = 0; ks < 3; ks++) {
            bfv8 ua = *(const bfv8*)&myU[l16 * ST + ks * 32 + quad * 8];
#pragma unroll
            for (int nt = 0; nt < 4; nt++) {
                bfv8 pvf = *(const bfv8*)&pevTs[(size_t)(nt * 16 + l16) * 2048 + (jbase - 1) + ks * 32 + quad * 8];
                o_acc[nt] = __builtin_amdgcn_mfma_f32_16x16x32_bf16(ua, pvf, o_acc[nt], 0, 0, 0);
            }
        }
    }

    // ---- epilogue: O / l, write bf16 attn-out in [B, L, D] layout
    const int b = bh >> 4, h = bh & 15;
#pragma unroll
    for (int nt = 0; nt < 4; nt++)
#pragma unroll
        for (int r = 0; r < 4; r++) {
            int q = 16 * s + quad * 4 + r;
            int d = nt * 16 + l16;
            Ob[((size_t)(b * 1024 + q)) * 1024 + h * 64 + d] = __float2bfloat16(o_acc[nt][r] / l_i[r]);
        }
}

// ---------------------------------------------------------------------------
extern "C" void kernel_launch(void* const* d_in, const int* in_sizes, int n_in,
                              void* d_out, int out_size, void* d_ws, size_t ws_size,
                              hipStream_t stream) {
    const float* x   = (const float*)d_in[0];
    const float* Wq  = (const float*)d_in[1];
    const float* Wk  = (const float*)d_in[2];
    const float* Wv  = (const float*)d_in[3];
    const float* Wo  = (const float*)d_in[4];
    const float* pek = (const float*)d_in[5];
    const float* pev = (const float*)d_in[6];

    const size_t MB = 1u << 20;
    char* ws = (char*)d_ws;
    bf16* xb    = (bf16*)(ws + 0);          // 8 MB; dead after QKV gemm -> reused as Ao
    bf16* Wqb   = (bf16*)(ws + 8  * MB);
    bf16* Wkb   = (bf16*)(ws + 10 * MB);
    bf16* Wvb   = (bf16*)(ws + 12 * MB);
    bf16* Wob   = (bf16*)(ws + 14 * MB);
    bf16* Qb    = (bf16*)(ws + 16 * MB);    // Q,K,V contiguous (z-offset in gemm epilogue)
    bf16* Kb    = (bf16*)(ws + 24 * MB);
    bf16* Vb    = (bf16*)(ws + 32 * MB);
    bf16* Vtb   = (bf16*)(ws + 40 * MB);
    bf16* pekb  = (bf16*)(ws + 48 * MB);            // 2049*64*2 B
    bf16* pevTs = (bf16*)(ws + 48 * MB + 512*1024); // 64*2048*2 B
    bf16* Ao    = xb;                               // aliased: x dead by then

    prep_cast<<<dim3(8192), 256, 0, stream>>>(x, Wq, Wk, Wv, Wo, xb, Wqb, Wkb, Wvb, Wob);
    prep_tables<<<dim3(2049), 64, 0, stream>>>(pek, pev, pekb, pevTs);
    gemm_bt2<<<dim3(8, 32, 3), 256, 0, stream>>>(xb, Wqb, Wkb, Wvb, Qb, nullptr, 1024, 0);
    transpose_v<<<dim3(16, 64), 256, 0, stream>>>(Vb, Vtb);
    attn_k<<<dim3(16, 64), 256, 0, stream>>>(Qb, Kb, Vtb, pekb, pevTs, Ao);
    gemm_bt2<<<dim3(8, 32, 1), 256, 0, stream>>>(Ao, Wob, nullptr, nullptr, nullptr, (float*)d_out, 1024, 1);
}

// Round 4
// 276.674 us; speedup vs baseline: 1.5671x; 1.1749x over previous
//
#include <hip/hip_runtime.h>
#include <hip/hip_bf16.h>

typedef __hip_bfloat16 bf16;
using bfv8 = __attribute__((ext_vector_type(8))) __bf16;
using f4_t = __attribute__((ext_vector_type(4))) float;

#define DEVI static __device__ __forceinline__

DEVI unsigned short f2bu(float f) {
    bf16 h = __float2bfloat16(f);
    return __builtin_bit_cast(unsigned short, h);
}
DEVI ushort4 f4_to_b4(float4 v) {
    ushort4 r;
    r.x = f2bu(v.x); r.y = f2bu(v.y); r.z = f2bu(v.z); r.w = f2bu(v.w);
    return r;
}
DEVI void gl2lds16(const void* g, void* l) {
    __builtin_amdgcn_global_load_lds((const __attribute__((address_space(1))) void*)g,
                                     (__attribute__((address_space(3))) void*)l, 16, 0, 0);
}

// ---------------------------------------------------------------------------
// prep_cast: fp32 -> bf16 for x (4M elems) and Wq/Wk/Wv/Wo (1M each).
// ---------------------------------------------------------------------------
__global__ __launch_bounds__(256) void prep_cast(
    const float* __restrict__ x, const float* __restrict__ wq, const float* __restrict__ wk,
    const float* __restrict__ wv, const float* __restrict__ wo,
    bf16* __restrict__ xb, bf16* __restrict__ wqb, bf16* __restrict__ wkb,
    bf16* __restrict__ wvb, bf16* __restrict__ wob)
{
    size_t i = (size_t)blockIdx.x * 256 + threadIdx.x;   // float4 index
    const size_t X4 = 1u << 20, W4 = 1u << 18;
    const float* src; bf16* dst; size_t off;
    if (i < X4)              { src = x;  dst = xb;  off = i; }
    else if (i < X4 + W4)    { src = wq; dst = wqb; off = i - X4; }
    else if (i < X4 + 2*W4)  { src = wk; dst = wkb; off = i - X4 - W4; }
    else if (i < X4 + 3*W4)  { src = wv; dst = wvb; off = i - X4 - 2*W4; }
    else                     { src = wo; dst = wob; off = i - X4 - 3*W4; }
    float4 v = ((const float4*)src)[off];
    ((ushort4*)dst)[off] = f4_to_b4(v);
}

// ---------------------------------------------------------------------------
// prep_tables: pekb[j][d] = bf16(pek[j][d]); pevTs[d][j] = bf16(pev[j+1][d])
// (transposed, -1 column shift so even jbase-1 gives 16B-aligned loads).
// ---------------------------------------------------------------------------
__global__ void prep_tables(const float* __restrict__ pek, const float* __restrict__ pev,
                            bf16* __restrict__ pekb, bf16* __restrict__ pevTs)
{
    int j = blockIdx.x, d = threadIdx.x;   // grid 2049 x 64
    pekb[j * 64 + d] = __float2bfloat16(pek[j * 64 + d]);
    if (j >= 1) pevTs[(size_t)d * 2048 + (j - 1)] = __float2bfloat16(pev[j * 64 + d]);
}

// ---------------------------------------------------------------------------
// transpose_v: Vb [bh][l][d] -> Vtb [bh][d][l], 64x64 LDS tiles.
// ---------------------------------------------------------------------------
__global__ __launch_bounds__(256) void transpose_v(const bf16* __restrict__ Vb, bf16* __restrict__ Vtb)
{
    __shared__ __align__(16) bf16 t[64][72];
    const int bh = blockIdx.y, l0 = blockIdx.x * 64;
    const int r = threadIdx.x >> 2, c0 = (threadIdx.x & 3) * 16;
    const bf16* src = Vb + ((size_t)(bh << 10) + l0 + r) * 64 + c0;
    *(int4*)&t[r][c0]     = *(const int4*)src;
    *(int4*)&t[r][c0 + 8] = *(const int4*)(src + 8);
    __syncthreads();
    int4 o[2]; bf16* ob = (bf16*)o;
#pragma unroll
    for (int j = 0; j < 16; j++) ob[j] = t[c0 + j][r];
    bf16* dst = Vtb + ((size_t)(bh << 6) + r) * 1024 + l0 + c0;
    *(int4*)dst = o[0]; *(int4*)(dst + 8) = o[1];
}

// ---------------------------------------------------------------------------
// NT GEMM (m97 structure): C[m][n] = sum_k A[m][k]*B[n][k], A/B bf16.
// 128x128 tile, BK=64, 4 waves 2x2, global_load_lds width=16.
// ---------------------------------------------------------------------------
__global__ __launch_bounds__(256) void gemm_bt2(
    const bf16* __restrict__ A,
    const bf16* __restrict__ B0, const bf16* __restrict__ B1, const bf16* __restrict__ B2,
    bf16* __restrict__ outb, float* __restrict__ outf, int K, int mode)
{
    __shared__ __align__(16) bf16 As[128 * 64];
    __shared__ __align__(16) bf16 Bs[128 * 64];

    const int tid  = threadIdx.x;
    const int lane = tid & 63, wave = tid >> 6;
    const int quad = lane >> 4, l16 = lane & 15;
    const int wr = wave >> 1, wc = wave & 1;
    const int m0 = blockIdx.y * 128, n0 = blockIdx.x * 128;
    const int z = blockIdx.z;
    const bf16* Bm = (z == 0) ? B0 : (z == 1) ? B1 : B2;

    f4_t zero = {0.f, 0.f, 0.f, 0.f};
    f4_t acc[4][4];
#pragma unroll
    for (int i = 0; i < 4; i++)
#pragma unroll
        for (int j = 0; j < 4; j++) acc[i][j] = zero;

    const int srow = 32 * wave + (lane >> 3);
    const int scol = (lane & 7) * 8;
    const bf16* Ag = A  + (size_t)(m0 + srow) * K + scol;
    const bf16* Bg = Bm + (size_t)(n0 + srow) * K + scol;

    for (int k0 = 0; k0 < K; k0 += 64) {
#pragma unroll
        for (int i = 0; i < 4; i++) {
            gl2lds16(Ag + (size_t)(8 * i) * K + k0, &As[(32 * wave + 8 * i) * 64]);
            gl2lds16(Bg + (size_t)(8 * i) * K + k0, &Bs[(32 * wave + 8 * i) * 64]);
        }
        __syncthreads();
#pragma unroll
        for (int ks = 0; ks < 2; ks++) {
            bfv8 af[4], bfr[4];
#pragma unroll
            for (int mt = 0; mt < 4; mt++)
                af[mt] = *(const bfv8*)&As[(wr * 64 + mt * 16 + l16) * 64 + ks * 32 + quad * 8];
#pragma unroll
            for (int nt = 0; nt < 4; nt++)
                bfr[nt] = *(const bfv8*)&Bs[(wc * 64 + nt * 16 + l16) * 64 + ks * 32 + quad * 8];
#pragma unroll
            for (int mt = 0; mt < 4; mt++)
#pragma unroll
                for (int nt = 0; nt < 4; nt++)
                    acc[mt][nt] = __builtin_amdgcn_mfma_f32_16x16x32_bf16(af[mt], bfr[nt], acc[mt][nt], 0, 0, 0);
        }
        __syncthreads();
    }

    if (mode == 0) {
        bf16* ob = outb + (size_t)z * (4 * 16 * 1024 * 64);
#pragma unroll
        for (int mt = 0; mt < 4; mt++)
#pragma unroll
            for (int nt = 0; nt < 4; nt++)
#pragma unroll
                for (int r = 0; r < 4; r++) {
                    int m = m0 + wr * 64 + mt * 16 + quad * 4 + r;
                    int n = n0 + wc * 64 + nt * 16 + l16;
                    int b = m >> 10, l = m & 1023, h = n >> 6, hd = n & 63;
                    ob[((size_t)(b * 16 + h) * 1024 + l) * 64 + hd] = __float2bfloat16(acc[mt][nt][r]);
                }
    } else {
#pragma unroll
        for (int mt = 0; mt < 4; mt++)
#pragma unroll
            for (int nt = 0; nt < 4; nt++)
#pragma unroll
                for (int r = 0; r < 4; r++) {
                    int m = m0 + wr * 64 + mt * 16 + quad * 4 + r;
                    int n = n0 + wc * 64 + nt * 16 + l16;
                    outf[(size_t)m * 1024 + n] = acc[mt][nt][r];
                }
    }
}

// ---------------------------------------------------------------------------
// attn_k v4: block = one bh, 4 waves = 4 adjacent strips s=4g+w (identical
// nkt=g+1 -> perfect intra-block balance). K-tile and Vt-tile are staged once
// per tile into LDS via global_load_lds (shared by all 4 waves); fragments
// read from LDS. Grid x=bh so each XCD (round-robin) sees only bh%8==const:
// 2 MB K/V working set per XCD -> L2-resident. pek/pev frags stay global
// (768 KB tables, L2/L1-hot, shared across all bh).
// Skew gather via shuffles; U zero-fill hoisted (band cols tile-invariant).
// ---------------------------------------------------------------------------
__global__ __launch_bounds__(256) void attn_k(
    const bf16* __restrict__ Qb, const bf16* __restrict__ Kb, const bf16* __restrict__ Vtb,
    const bf16* __restrict__ pekb, const bf16* __restrict__ pevTs, bf16* __restrict__ Ob)
{
    constexpr int ST = 104;                       // U stride (208B rows, 16B-aligned)
    __shared__ __align__(16) bf16 Ks[64 * 64];    // K tile  [kk][d]
    __shared__ __align__(16) bf16 Vs[64 * 64];    // Vt tile [d][kk]
    __shared__ __align__(16) bf16 sU[4][16 * ST]; // banded U (16x96 used), per wave
    __shared__ __align__(16) bf16 sP[4][16 * 72]; // P (16x64), per wave

    const int tid  = threadIdx.x;
    const int lane = tid & 63, wave = tid >> 6;
    const int quad = lane >> 4, l16 = lane & 15;
    const int bh = blockIdx.x;
    const int g  = 15 - blockIdx.y;               // heavy blocks dispatched first
    const int s  = 4 * g + wave;
    const int nkt = g + 1;

    bf16* myU = sU[wave];
    bf16* myP = sP[wave];

    // ---- zero U once (band positions are tile-invariant; complement stays 0)
    {
        int* p = (int*)myU;
#pragma unroll
        for (int i = 0; i < 13; i++) p[lane + 64 * i] = 0;
    }

    // ---- Q A-fragments, pre-scaled by 1/8
    bfv8 qf[2];
    {
        const bf16* qp = Qb + ((size_t)bh * 1024 + 16 * s + l16) * 64 + quad * 8;
        qf[0] = *(const bfv8*)qp;
        qf[1] = *(const bfv8*)(qp + 32);
#pragma unroll
        for (int j = 0; j < 8; j++) {
            qf[0][j] = (__bf16)((float)qf[0][j] * 0.125f);
            qf[1][j] = (__bf16)((float)qf[1][j] * 0.125f);
        }
    }

    f4_t zero = {0.f, 0.f, 0.f, 0.f};
    f4_t o_acc[4];
    float m_i[4], l_i[4];
#pragma unroll
    for (int i = 0; i < 4; i++) { o_acc[i] = zero; m_i[i] = -1e30f; l_i[i] = 0.f; }

    const bf16* Kbh = Kb  + (size_t)bh * 1024 * 64;
    const bf16* Vbh = Vtb + (size_t)bh * 64 * 1024;

    for (int kt = 0; kt < nkt; kt++) {
        const int k0 = kt << 6;
        const int jbase = k0 - 16 * s + 1009;     // odd, in [1, 1009]

        // ---- stage K tile + Vt tile (8 KB each) via global_load_lds.
        // chunk c = wave*64+lane+256*i -> row c>>3, col (c&7)*8; LDS base uniform.
#pragma unroll
        for (int i = 0; i < 2; i++) {
            const int rb = 8 * wave + 32 * i;                 // row base of this instr
            const int row = rb + (lane >> 3), col = (lane & 7) * 8;
            gl2lds16(Kbh + (size_t)(k0 + row) * 64 + col, &Ks[(64 * wave + 256 * i) * 8]);
            gl2lds16(Vbh + (size_t)row * 1024 + k0 + col, &Vs[(64 * wave + 256 * i) * 8]);
        }
        __syncthreads();

        // ---- S1 = Qs K^T (4 frags, LDS), T = Qs Pek^T (5 frags, global)
        f4_t s1[4], tt[5];
#pragma unroll
        for (int i = 0; i < 4; i++) s1[i] = zero;
#pragma unroll
        for (int i = 0; i < 5; i++) tt[i] = zero;
#pragma unroll
        for (int ks = 0; ks < 2; ks++) {
#pragma unroll
            for (int nt = 0; nt < 4; nt++) {
                bfv8 kf = *(const bfv8*)&Ks[(nt * 16 + l16) * 64 + ks * 32 + quad * 8];
                s1[nt] = __builtin_amdgcn_mfma_f32_16x16x32_bf16(qf[ks], kf, s1[nt], 0, 0, 0);
            }
#pragma unroll
            for (int nt = 0; nt < 5; nt++) {
                bfv8 pf = *(const bfv8*)&pekb[(size_t)(jbase + nt * 16 + l16) * 64 + ks * 32 + quad * 8];
                tt[nt] = __builtin_amdgcn_mfma_f32_16x16x32_bf16(qf[ks], pf, tt[nt], 0, 0, 0);
            }
        }

        // ---- skew gather via shuffles + causal mask (all pre-scaled)
        float sc[4][4];
#pragma unroll
        for (int r = 0; r < 4; r++) {
            int qq = quad * 4 + r;
            int t  = l16 + 15 - qq;                    // in [0,30]
            int srcl = quad * 16 + (t & 15);
            bool lo = (t < 16);
#pragma unroll
            for (int nt = 0; nt < 4; nt++) {
                float a = __shfl(tt[nt][r], srcl, 64);
                float b = __shfl(tt[nt + 1][r], srcl, 64);
                float s2 = lo ? a : b;
                float v = s1[nt][r] + s2;
                int kk = nt * 16 + l16;
                if (k0 + kk > 16 * s + qq) v = -1e30f;
                sc[nt][r] = v;
            }
        }

        // ---- online softmax (row = quad*4+r; reduce over l16 via xor<16)
        float alpha[4];
#pragma unroll
        for (int r = 0; r < 4; r++) {
            float mt = fmaxf(fmaxf(sc[0][r], sc[1][r]), fmaxf(sc[2][r], sc[3][r]));
            mt = fmaxf(mt, __shfl_xor(mt, 1));
            mt = fmaxf(mt, __shfl_xor(mt, 2));
            mt = fmaxf(mt, __shfl_xor(mt, 4));
            mt = fmaxf(mt, __shfl_xor(mt, 8));
            float mnew = fmaxf(m_i[r], mt);
            alpha[r] = __expf(m_i[r] - mnew);
            m_i[r] = mnew;
        }
#pragma unroll
        for (int nt = 0; nt < 4; nt++)
#pragma unroll
            for (int r = 0; r < 4; r++)
                sc[nt][r] = __expf(sc[nt][r] - m_i[r]);
#pragma unroll
        for (int r = 0; r < 4; r++) {
            float rs = sc[0][r] + sc[1][r] + sc[2][r] + sc[3][r];
            rs += __shfl_xor(rs, 1);
            rs += __shfl_xor(rs, 2);
            rs += __shfl_xor(rs, 4);
            rs += __shfl_xor(rs, 8);
            l_i[r] = l_i[r] * alpha[r] + rs;
#pragma unroll
            for (int nt = 0; nt < 4; nt++) o_acc[nt][r] *= alpha[r];
        }

        // ---- scatter P (row-major) and banded U (wave-private LDS, no barrier)
#pragma unroll
        for (int nt = 0; nt < 4; nt++)
#pragma unroll
            for (int r = 0; r < 4; r++) {
                int qq = quad * 4 + r;
                int kk = nt * 16 + l16;
                bf16 pb = __float2bfloat16(sc[nt][r]);
                myP[qq * 72 + kk] = pb;
                myU[qq * ST + kk - qq + 15] = pb;
            }

        // ---- O += P V (K=64, V frags from LDS) ; O += U Pev (K=96, global)
#pragma unroll
        for (int ks = 0; ks < 2; ks++) {
            bfv8 pa = *(const bfv8*)&myP[l16 * 72 + ks * 32 + quad * 8];
#pragma unroll
            for (int nt = 0; nt < 4; nt++) {
                bfv8 vf = *(const bfv8*)&Vs[(nt * 16 + l16) * 64 + ks * 32 + quad * 8];
                o_acc[nt] = __builtin_amdgcn_mfma_f32_16x16x32_bf16(pa, vf, o_acc[nt], 0, 0, 0);
            }
        }
#pragma unroll
        for (int ks = 0; ks < 3; ks++) {
            bfv8 ua = *(const bfv8*)&myU[l16 * ST + ks * 32 + quad * 8];
#pragma unroll
            for (int nt = 0; nt < 4; nt++) {
                bfv8 pvf = *(const bfv8*)&pevTs[(size_t)(nt * 16 + l16) * 2048 + (jbase - 1) + ks * 32 + quad * 8];
                o_acc[nt] = __builtin_amdgcn_mfma_f32_16x16x32_bf16(ua, pvf, o_acc[nt], 0, 0, 0);
            }
        }
        __syncthreads();   // Ks/Vs consumed; safe to restage next tile
    }

    // ---- epilogue: O / l, write bf16 attn-out in [B, L, D] layout
    const int b = bh >> 4, h = bh & 15;
#pragma unroll
    for (int nt = 0; nt < 4; nt++)
#pragma unroll
        for (int r = 0; r < 4; r++) {
            int q = 16 * s + quad * 4 + r;
            int d = nt * 16 + l16;
            Ob[((size_t)(b * 1024 + q)) * 1024 + h * 64 + d] = __float2bfloat16(o_acc[nt][r] / l_i[r]);
        }
}

// ---------------------------------------------------------------------------
extern "C" void kernel_launch(void* const* d_in, const int* in_sizes, int n_in,
                              void* d_out, int out_size, void* d_ws, size_t ws_size,
                              hipStream_t stream) {
    const float* x   = (const float*)d_in[0];
    const float* Wq  = (const float*)d_in[1];
    const float* Wk  = (const float*)d_in[2];
    const float* Wv  = (const float*)d_in[3];
    const float* Wo  = (const float*)d_in[4];
    const float* pek = (const float*)d_in[5];
    const float* pev = (const float*)d_in[6];

    const size_t MB = 1u << 20;
    char* ws = (char*)d_ws;
    bf16* xb    = (bf16*)(ws + 0);          // 8 MB; dead after QKV gemm -> reused as Ao
    bf16* Wqb   = (bf16*)(ws + 8  * MB);
    bf16* Wkb   = (bf16*)(ws + 10 * MB);
    bf16* Wvb   = (bf16*)(ws + 12 * MB);
    bf16* Wob   = (bf16*)(ws + 14 * MB);
    bf16* Qb    = (bf16*)(ws + 16 * MB);    // Q,K,V contiguous (z-offset in gemm epilogue)
    bf16* Kb    = (bf16*)(ws + 24 * MB);
    bf16* Vb    = (bf16*)(ws + 32 * MB);
    bf16* Vtb   = (bf16*)(ws + 40 * MB);
    bf16* pekb  = (bf16*)(ws + 48 * MB);            // 2049*64*2 B
    bf16* pevTs = (bf16*)(ws + 48 * MB + 512*1024); // 64*2048*2 B
    bf16* Ao    = xb;                               // aliased: x dead by then

    prep_cast<<<dim3(8192), 256, 0, stream>>>(x, Wq, Wk, Wv, Wo, xb, Wqb, Wkb, Wvb, Wob);
    prep_tables<<<dim3(2049), 64, 0, stream>>>(pek, pev, pekb, pevTs);
    gemm_bt2<<<dim3(8, 32, 3), 256, 0, stream>>>(xb, Wqb, Wkb, Wvb, Qb, nullptr, 1024, 0);
    transpose_v<<<dim3(16, 64), 256, 0, stream>>>(Vb, Vtb);
    attn_k<<<dim3(64, 16), 256, 0, stream>>>(Qb, Kb, Vtb, pekb, pevTs, Ao);
    gemm_bt2<<<dim3(8, 32, 1), 256, 0, stream>>>(Ao, Wob, nullptr, nullptr, nullptr, (float*)d_out, 1024, 1);
}

// Round 5
// 276.427 us; speedup vs baseline: 1.5685x; 1.0009x over previous
//
#include <hip/hip_runtime.h>
#include <hip/hip_bf16.h>

typedef __hip_bfloat16 bf16;
using bfv8 = __attribute__((ext_vector_type(8))) __bf16;
using f4_t = __attribute__((ext_vector_type(4))) float;

#define DEVI static __device__ __forceinline__

DEVI unsigned short f2bu(float f) {
    bf16 h = __float2bfloat16(f);
    return __builtin_bit_cast(unsigned short, h);
}
DEVI ushort4 f4_to_b4(float4 v) {
    ushort4 r;
    r.x = f2bu(v.x); r.y = f2bu(v.y); r.z = f2bu(v.z); r.w = f2bu(v.w);
    return r;
}
DEVI void gl2lds16(const void* g, void* l) {
    __builtin_amdgcn_global_load_lds((const __attribute__((address_space(1))) void*)g,
                                     (__attribute__((address_space(3))) void*)l, 16, 0, 0);
}

// ---------------------------------------------------------------------------
// prep_cast: fp32 -> bf16 for x (4M elems) and Wq/Wk/Wv/Wo (1M each).
// ---------------------------------------------------------------------------
__global__ __launch_bounds__(256) void prep_cast(
    const float* __restrict__ x, const float* __restrict__ wq, const float* __restrict__ wk,
    const float* __restrict__ wv, const float* __restrict__ wo,
    bf16* __restrict__ xb, bf16* __restrict__ wqb, bf16* __restrict__ wkb,
    bf16* __restrict__ wvb, bf16* __restrict__ wob)
{
    size_t i = (size_t)blockIdx.x * 256 + threadIdx.x;   // float4 index
    const size_t X4 = 1u << 20, W4 = 1u << 18;
    const float* src; bf16* dst; size_t off;
    if (i < X4)              { src = x;  dst = xb;  off = i; }
    else if (i < X4 + W4)    { src = wq; dst = wqb; off = i - X4; }
    else if (i < X4 + 2*W4)  { src = wk; dst = wkb; off = i - X4 - W4; }
    else if (i < X4 + 3*W4)  { src = wv; dst = wvb; off = i - X4 - 2*W4; }
    else                     { src = wo; dst = wob; off = i - X4 - 3*W4; }
    float4 v = ((const float4*)src)[off];
    ((ushort4*)dst)[off] = f4_to_b4(v);
}

// ---------------------------------------------------------------------------
// prep_tables: pekb[j][d] = bf16(pek[j][d]); pevTs[d][j] = bf16(pev[j+1][d])
// (transposed, -1 column shift so even jbase-1 gives 16B-aligned loads).
// ---------------------------------------------------------------------------
__global__ void prep_tables(const float* __restrict__ pek, const float* __restrict__ pev,
                            bf16* __restrict__ pekb, bf16* __restrict__ pevTs)
{
    int j = blockIdx.x, d = threadIdx.x;   // grid 2049 x 64
    pekb[j * 64 + d] = __float2bfloat16(pek[j * 64 + d]);
    if (j >= 1) pevTs[(size_t)d * 2048 + (j - 1)] = __float2bfloat16(pev[j * 64 + d]);
}

// ---------------------------------------------------------------------------
// transpose_v: Vb [bh][l][d] -> Vtb [bh][d][l], 64x64 LDS tiles.
// ---------------------------------------------------------------------------
__global__ __launch_bounds__(256) void transpose_v(const bf16* __restrict__ Vb, bf16* __restrict__ Vtb)
{
    __shared__ __align__(16) bf16 t[64][72];
    const int bh = blockIdx.y, l0 = blockIdx.x * 64;
    const int r = threadIdx.x >> 2, c0 = (threadIdx.x & 3) * 16;
    const bf16* src = Vb + ((size_t)(bh << 10) + l0 + r) * 64 + c0;
    *(int4*)&t[r][c0]     = *(const int4*)src;
    *(int4*)&t[r][c0 + 8] = *(const int4*)(src + 8);
    __syncthreads();
    int4 o[2]; bf16* ob = (bf16*)o;
#pragma unroll
    for (int j = 0; j < 16; j++) ob[j] = t[c0 + j][r];
    bf16* dst = Vtb + ((size_t)(bh << 6) + r) * 1024 + l0 + c0;
    *(int4*)dst = o[0]; *(int4*)(dst + 8) = o[1];
}

// ---------------------------------------------------------------------------
// NT GEMM (m97 structure): C[m][n] = sum_k A[m][k]*B[n][k], A/B bf16.
// 128x128 tile, BK=64, 4 waves 2x2, global_load_lds width=16.
// ---------------------------------------------------------------------------
__global__ __launch_bounds__(256) void gemm_bt2(
    const bf16* __restrict__ A,
    const bf16* __restrict__ B0, const bf16* __restrict__ B1, const bf16* __restrict__ B2,
    bf16* __restrict__ outb, float* __restrict__ outf, int K, int mode)
{
    __shared__ __align__(16) bf16 As[128 * 64];
    __shared__ __align__(16) bf16 Bs[128 * 64];

    const int tid  = threadIdx.x;
    const int lane = tid & 63, wave = tid >> 6;
    const int quad = lane >> 4, l16 = lane & 15;
    const int wr = wave >> 1, wc = wave & 1;
    const int m0 = blockIdx.y * 128, n0 = blockIdx.x * 128;
    const int z = blockIdx.z;
    const bf16* Bm = (z == 0) ? B0 : (z == 1) ? B1 : B2;

    f4_t zero = {0.f, 0.f, 0.f, 0.f};
    f4_t acc[4][4];
#pragma unroll
    for (int i = 0; i < 4; i++)
#pragma unroll
        for (int j = 0; j < 4; j++) acc[i][j] = zero;

    const int srow = 32 * wave + (lane >> 3);
    const int scol = (lane & 7) * 8;
    const bf16* Ag = A  + (size_t)(m0 + srow) * K + scol;
    const bf16* Bg = Bm + (size_t)(n0 + srow) * K + scol;

    for (int k0 = 0; k0 < K; k0 += 64) {
#pragma unroll
        for (int i = 0; i < 4; i++) {
            gl2lds16(Ag + (size_t)(8 * i) * K + k0, &As[(32 * wave + 8 * i) * 64]);
            gl2lds16(Bg + (size_t)(8 * i) * K + k0, &Bs[(32 * wave + 8 * i) * 64]);
        }
        __syncthreads();
#pragma unroll
        for (int ks = 0; ks < 2; ks++) {
            bfv8 af[4], bfr[4];
#pragma unroll
            for (int mt = 0; mt < 4; mt++)
                af[mt] = *(const bfv8*)&As[(wr * 64 + mt * 16 + l16) * 64 + ks * 32 + quad * 8];
#pragma unroll
            for (int nt = 0; nt < 4; nt++)
                bfr[nt] = *(const bfv8*)&Bs[(wc * 64 + nt * 16 + l16) * 64 + ks * 32 + quad * 8];
#pragma unroll
            for (int mt = 0; mt < 4; mt++)
#pragma unroll
                for (int nt = 0; nt < 4; nt++)
                    acc[mt][nt] = __builtin_amdgcn_mfma_f32_16x16x32_bf16(af[mt], bfr[nt], acc[mt][nt], 0, 0, 0);
        }
        __syncthreads();
    }

    if (mode == 0) {
        bf16* ob = outb + (size_t)z * (4 * 16 * 1024 * 64);
#pragma unroll
        for (int mt = 0; mt < 4; mt++)
#pragma unroll
            for (int nt = 0; nt < 4; nt++)
#pragma unroll
                for (int r = 0; r < 4; r++) {
                    int m = m0 + wr * 64 + mt * 16 + quad * 4 + r;
                    int n = n0 + wc * 64 + nt * 16 + l16;
                    int b = m >> 10, l = m & 1023, h = n >> 6, hd = n & 63;
                    ob[((size_t)(b * 16 + h) * 1024 + l) * 64 + hd] = __float2bfloat16(acc[mt][nt][r]);
                }
    } else {
#pragma unroll
        for (int mt = 0; mt < 4; mt++)
#pragma unroll
            for (int nt = 0; nt < 4; nt++)
#pragma unroll
                for (int r = 0; r < 4; r++) {
                    int m = m0 + wr * 64 + mt * 16 + quad * 4 + r;
                    int n = n0 + wc * 64 + nt * 16 + l16;
                    outf[(size_t)m * 1024 + n] = acc[mt][nt][r];
                }
    }
}

// ---------------------------------------------------------------------------
// attn_k v5: block = one bh; two balanced phases (strip pairing).
//   phase 0: strips 4*gp+w     (gp+1 tiles)
//   phase 1: strips 4*(15-gp)+w (16-gp tiles)   => every block: 17 tiles.
// Grid 64x8 = 512 identical blocks (2/CU, no tail). XCD sees bh%8 only.
// Ks/Vs staged via global_load_lds with XOR swizzle:
//   storage[r][cg] = logical[r][cg ^ (r&7)]  (swizzle applied on the global
//   source address, since the LDS dest of global_load_lds is forced
//   contiguous). Fragment reads xor the colgroup with l16&7 -> each
//   consecutive-8-lane phase of ds_read_b128 hits all 8 bank groups.
// Skew gather via shuffles; U zero-fill hoisted (band cols invariant).
// ---------------------------------------------------------------------------
__global__ __launch_bounds__(256) void attn_k(
    const bf16* __restrict__ Qb, const bf16* __restrict__ Kb, const bf16* __restrict__ Vtb,
    const bf16* __restrict__ pekb, const bf16* __restrict__ pevTs, bf16* __restrict__ Ob)
{
    constexpr int ST = 104;                       // U stride (208B rows, 16B-aligned)
    __shared__ __align__(16) bf16 Ks[64 * 64];    // K tile  [kk][d], xor-swizzled
    __shared__ __align__(16) bf16 Vs[64 * 64];    // Vt tile [d][kk], xor-swizzled
    __shared__ __align__(16) bf16 sU[4][16 * ST]; // banded U (16x96 used), per wave
    __shared__ __align__(16) bf16 sP[4][16 * 72]; // P (16x64), per wave

    const int tid  = threadIdx.x;
    const int lane = tid & 63, wave = tid >> 6;
    const int quad = lane >> 4, l16 = lane & 15;
    const int bh = blockIdx.x;
    const int gp = blockIdx.y;                    // 0..7 pair index

    bf16* myU = sU[wave];
    bf16* myP = sP[wave];

    // staging lane geometry (swizzle is wave/instr-invariant)
    const int srow8 = lane >> 3;                  // 0..7
    const int scg   = (lane & 7) ^ srow8;         // swizzled colgroup for the fetch
    const int x8    = l16 & 7;                    // frag-read xor term

    // ---- zero U once (band positions invariant across tiles AND phases)
    {
        int* p = (int*)myU;
#pragma unroll
        for (int i = 0; i < 13; i++) p[lane + 64 * i] = 0;
    }

    const bf16* Kbh = Kb  + (size_t)bh * 1024 * 64;
    const bf16* Vbh = Vtb + (size_t)bh * 64 * 1024;
    const int b = bh >> 4, h = bh & 15;

    f4_t zero = {0.f, 0.f, 0.f, 0.f};

    for (int p = 0; p < 2; p++) {
        const int g = p ? 15 - gp : gp;
        const int s = 4 * g + wave;
        const int nkt = g + 1;

        // ---- Q A-fragments for this phase's strip, pre-scaled by 1/8
        bfv8 qf[2];
        {
            const bf16* qp = Qb + ((size_t)bh * 1024 + 16 * s + l16) * 64 + quad * 8;
            qf[0] = *(const bfv8*)qp;
            qf[1] = *(const bfv8*)(qp + 32);
#pragma unroll
            for (int j = 0; j < 8; j++) {
                qf[0][j] = (__bf16)((float)qf[0][j] * 0.125f);
                qf[1][j] = (__bf16)((float)qf[1][j] * 0.125f);
            }
        }

        f4_t o_acc[4];
        float m_i[4], l_i[4];
#pragma unroll
        for (int i = 0; i < 4; i++) { o_acc[i] = zero; m_i[i] = -1e30f; l_i[i] = 0.f; }

        for (int kt = 0; kt < nkt; kt++) {
            const int k0 = kt << 6;
            const int jbase = k0 - 16 * s + 1009;     // odd, in [1, 1009]

            // ---- stage K tile + Vt tile (8 KB each), xor-swizzled source
#pragma unroll
            for (int i = 0; i < 2; i++) {
                const int row = 8 * wave + 32 * i + srow8;
                gl2lds16(Kbh + (size_t)(k0 + row) * 64 + scg * 8, &Ks[(64 * wave + 256 * i) * 8]);
                gl2lds16(Vbh + (size_t)row * 1024 + k0 + scg * 8, &Vs[(64 * wave + 256 * i) * 8]);
            }
            __syncthreads();

            // ---- S1 = Qs K^T (4 frags, LDS), T = Qs Pek^T (5 frags, global)
            f4_t s1[4], tt[5];
#pragma unroll
            for (int i = 0; i < 4; i++) s1[i] = zero;
#pragma unroll
            for (int i = 0; i < 5; i++) tt[i] = zero;
#pragma unroll
            for (int ks = 0; ks < 2; ks++) {
#pragma unroll
                for (int nt = 0; nt < 4; nt++) {
                    bfv8 kf = *(const bfv8*)&Ks[(nt * 16 + l16) * 64 + ((ks * 4 + quad) ^ x8) * 8];
                    s1[nt] = __builtin_amdgcn_mfma_f32_16x16x32_bf16(qf[ks], kf, s1[nt], 0, 0, 0);
                }
#pragma unroll
                for (int nt = 0; nt < 5; nt++) {
                    bfv8 pf = *(const bfv8*)&pekb[(size_t)(jbase + nt * 16 + l16) * 64 + ks * 32 + quad * 8];
                    tt[nt] = __builtin_amdgcn_mfma_f32_16x16x32_bf16(qf[ks], pf, tt[nt], 0, 0, 0);
                }
            }

            // ---- skew gather via shuffles + causal mask (all pre-scaled)
            float sc[4][4];
#pragma unroll
            for (int r = 0; r < 4; r++) {
                int qq = quad * 4 + r;
                int t  = l16 + 15 - qq;                    // in [0,30]
                int srcl = quad * 16 + (t & 15);
                bool lo = (t < 16);
#pragma unroll
                for (int nt = 0; nt < 4; nt++) {
                    float a = __shfl(tt[nt][r], srcl, 64);
                    float bv = __shfl(tt[nt + 1][r], srcl, 64);
                    float s2 = lo ? a : bv;
                    float v = s1[nt][r] + s2;
                    int kk = nt * 16 + l16;
                    if (k0 + kk > 16 * s + qq) v = -1e30f;
                    sc[nt][r] = v;
                }
            }

            // ---- online softmax (row = quad*4+r; reduce over l16 via xor<16)
            float alpha[4];
#pragma unroll
            for (int r = 0; r < 4; r++) {
                float mt = fmaxf(fmaxf(sc[0][r], sc[1][r]), fmaxf(sc[2][r], sc[3][r]));
                mt = fmaxf(mt, __shfl_xor(mt, 1));
                mt = fmaxf(mt, __shfl_xor(mt, 2));
                mt = fmaxf(mt, __shfl_xor(mt, 4));
                mt = fmaxf(mt, __shfl_xor(mt, 8));
                float mnew = fmaxf(m_i[r], mt);
                alpha[r] = __expf(m_i[r] - mnew);
                m_i[r] = mnew;
            }
#pragma unroll
            for (int nt = 0; nt < 4; nt++)
#pragma unroll
                for (int r = 0; r < 4; r++)
                    sc[nt][r] = __expf(sc[nt][r] - m_i[r]);
#pragma unroll
            for (int r = 0; r < 4; r++) {
                float rs = sc[0][r] + sc[1][r] + sc[2][r] + sc[3][r];
                rs += __shfl_xor(rs, 1);
                rs += __shfl_xor(rs, 2);
                rs += __shfl_xor(rs, 4);
                rs += __shfl_xor(rs, 8);
                l_i[r] = l_i[r] * alpha[r] + rs;
#pragma unroll
                for (int nt = 0; nt < 4; nt++) o_acc[nt][r] *= alpha[r];
            }

            // ---- scatter P (row-major) and banded U (wave-private, no barrier)
#pragma unroll
            for (int nt = 0; nt < 4; nt++)
#pragma unroll
                for (int r = 0; r < 4; r++) {
                    int qq = quad * 4 + r;
                    int kk = nt * 16 + l16;
                    bf16 pb = __float2bfloat16(sc[nt][r]);
                    myP[qq * 72 + kk] = pb;
                    myU[qq * ST + kk - qq + 15] = pb;
                }

            // ---- O += P V (K=64, swizzled LDS frags) ; O += U Pev (K=96, global)
#pragma unroll
            for (int ks = 0; ks < 2; ks++) {
                bfv8 pa = *(const bfv8*)&myP[l16 * 72 + ks * 32 + quad * 8];
#pragma unroll
                for (int nt = 0; nt < 4; nt++) {
                    bfv8 vf = *(const bfv8*)&Vs[(nt * 16 + l16) * 64 + ((ks * 4 + quad) ^ x8) * 8];
                    o_acc[nt] = __builtin_amdgcn_mfma_f32_16x16x32_bf16(pa, vf, o_acc[nt], 0, 0, 0);
                }
            }
#pragma unroll
            for (int ks = 0; ks < 3; ks++) {
                bfv8 ua = *(const bfv8*)&myU[l16 * ST + ks * 32 + quad * 8];
#pragma unroll
                for (int nt = 0; nt < 4; nt++) {
                    bfv8 pvf = *(const bfv8*)&pevTs[(size_t)(nt * 16 + l16) * 2048 + (jbase - 1) + ks * 32 + quad * 8];
                    o_acc[nt] = __builtin_amdgcn_mfma_f32_16x16x32_bf16(ua, pvf, o_acc[nt], 0, 0, 0);
                }
            }
            __syncthreads();   // Ks/Vs consumed; safe to restage next tile/phase
        }

        // ---- phase epilogue: O / l, write bf16 attn-out in [B, L, D] layout
#pragma unroll
        for (int nt = 0; nt < 4; nt++)
#pragma unroll
            for (int r = 0; r < 4; r++) {
                int q = 16 * s + quad * 4 + r;
                int d = nt * 16 + l16;
                Ob[((size_t)(b * 1024 + q)) * 1024 + h * 64 + d] = __float2bfloat16(o_acc[nt][r] / l_i[r]);
            }
    }
}

// ---------------------------------------------------------------------------
extern "C" void kernel_launch(void* const* d_in, const int* in_sizes, int n_in,
                              void* d_out, int out_size, void* d_ws, size_t ws_size,
                              hipStream_t stream) {
    const float* x   = (const float*)d_in[0];
    const float* Wq  = (const float*)d_in[1];
    const float* Wk  = (const float*)d_in[2];
    const float* Wv  = (const float*)d_in[3];
    const float* Wo  = (const float*)d_in[4];
    const float* pek = (const float*)d_in[5];
    const float* pev = (const float*)d_in[6];

    const size_t MB = 1u << 20;
    char* ws = (char*)d_ws;
    bf16* xb    = (bf16*)(ws + 0);          // 8 MB; dead after QKV gemm -> reused as Ao
    bf16* Wqb   = (bf16*)(ws + 8  * MB);
    bf16* Wkb   = (bf16*)(ws + 10 * MB);
    bf16* Wvb   = (bf16*)(ws + 12 * MB);
    bf16* Wob   = (bf16*)(ws + 14 * MB);
    bf16* Qb    = (bf16*)(ws + 16 * MB);    // Q,K,V contiguous (z-offset in gemm epilogue)
    bf16* Kb    = (bf16*)(ws + 24 * MB);
    bf16* Vb    = (bf16*)(ws + 32 * MB);
    bf16* Vtb   = (bf16*)(ws + 40 * MB);
    bf16* pekb  = (bf16*)(ws + 48 * MB);            // 2049*64*2 B
    bf16* pevTs = (bf16*)(ws + 48 * MB + 512*1024); // 64*2048*2 B
    bf16* Ao    = xb;                               // aliased: x dead by then

    prep_cast<<<dim3(8192), 256, 0, stream>>>(x, Wq, Wk, Wv, Wo, xb, Wqb, Wkb, Wvb, Wob);
    prep_tables<<<dim3(2049), 64, 0, stream>>>(pek, pev, pekb, pevTs);
    gemm_bt2<<<dim3(8, 32, 3), 256, 0, stream>>>(xb, Wqb, Wkb, Wvb, Qb, nullptr, 1024, 0);
    transpose_v<<<dim3(16, 64), 256, 0, stream>>>(Vb, Vtb);
    attn_k<<<dim3(64, 8), 256, 0, stream>>>(Qb, Kb, Vtb, pekb, pevTs, Ao);
    gemm_bt2<<<dim3(8, 32, 1), 256, 0, stream>>>(Ao, Wob, nullptr, nullptr, nullptr, (float*)d_out, 1024, 1);
}